// Round 2
// baseline (240.545 us; speedup 1.0000x reference)
//
#include <hip/hip_runtime.h>
#include <hip/hip_bf16.h>

#define B_ 8
#define L_ 2048
#define D_ 128
#define BL_ (B_ * L_)
#define LDSTR 132
#define MSPL 8

// ---------------- Kernel 1: L2 normalize rows ----------------
__global__ void k_normalize(const float* __restrict__ ctx,
                            float* __restrict__ cn, float* __restrict__ en) {
    int wid  = blockIdx.x * 4 + (threadIdx.x >> 6);
    int lane = threadIdx.x & 63;
    int b   = wid / (2 * L_);
    int rem = wid % (2 * L_);
    int c   = rem / L_;
    int l   = rem % L_;

    const float* src = ctx + (size_t)wid * D_;
    float2 v = ((const float2*)src)[lane];
    float ss = v.x * v.x + v.y * v.y;
    #pragma unroll
    for (int off = 32; off; off >>= 1) ss += __shfl_down(ss, off, 64);
    ss = __shfl(ss, 0, 64);
    float inv = 1.0f / fmaxf(sqrtf(ss), 1e-8f);
    float* dst = (c == 0 ? cn : en) + (size_t)(b * L_ + l) * D_;
    ((float2*)dst)[lane] = make_float2(v.x * inv, v.y * inv);
}

// ---------------- Kernel 2: g[r] = relu(X[r]@W1+b1)@W2 + b2 for all 2*BL rows ----------------
// X = [cn ; en] (contiguous in ws). 128x128 register-tiled GEMM per block, K=128.
__global__ __launch_bounds__(256, 4) void k_feval(
        const float* __restrict__ X,
        const float* __restrict__ W1, const float* __restrict__ b1,
        const float* __restrict__ W2, const float* __restrict__ b2,
        float* __restrict__ g) {
    __shared__ __align__(16) char smem[2 * 32 * LDSTR * 4];
    float (*As)[LDSTR] = (float(*)[LDSTR])smem;
    float (*Bs)[LDSTR] = (float(*)[LDSTR])(smem + 32 * LDSTR * 4);
    float (*redv)[16]  = (float(*)[16])smem;

    int tid = threadIdx.x;
    int tx = tid & 15, ty = tid >> 4;
    int r  = tid >> 3;        // 0..31
    int kg = tid & 7;         // 0..7
    int row0 = blockIdx.x * 128;

    const float* Abase = X + (size_t)row0 * D_;

    float acc[8][8];
    #pragma unroll
    for (int i = 0; i < 8; ++i)
        #pragma unroll
        for (int j = 0; j < 8; ++j) acc[i][j] = 0.0f;

    for (int kc = 0; kc < 4; ++kc) {
        __syncthreads();
        // A tile: rows of X, k-permuted store (k = 4*kg+i -> phys 8*i+kg)
        #pragma unroll
        for (int p = 0; p < 4; ++p) {
            int rr = r + 32 * p;
            float4 v = *(const float4*)(Abase + (size_t)rr * D_ + kc * 32 + kg * 4);
            As[kg][rr]      = v.x;
            As[8 + kg][rr]  = v.y;
            As[16 + kg][rr] = v.z;
            As[24 + kg][rr] = v.w;
        }
        // B tile: rows of W1 (k-major already), same perm: phys = (kr&3)*8 + (kr>>2)
        {
            int kr = r;
            int phys = (kr & 3) * 8 + (kr >> 2);
            const float* src = W1 + (size_t)(kc * 32 + kr) * D_ + kg * 16;
            #pragma unroll
            for (int q = 0; q < 4; ++q)
                *(float4*)&Bs[phys][kg * 16 + q * 4] = *(const float4*)(src + q * 4);
        }
        __syncthreads();
        #pragma unroll
        for (int k = 0; k < 32; ++k) {
            float a[8], bb[8];
            *(float4*)&a[0]  = *(const float4*)&As[k][ty * 8];
            *(float4*)&a[4]  = *(const float4*)&As[k][ty * 8 + 4];
            *(float4*)&bb[0] = *(const float4*)&Bs[k][tx * 4];
            *(float4*)&bb[4] = *(const float4*)&Bs[k][64 + tx * 4];
            #pragma unroll
            for (int i = 0; i < 8; ++i)
                #pragma unroll
                for (int j = 0; j < 8; ++j)
                    acc[i][j] = fmaf(a[i], bb[j], acc[i][j]);
        }
    }

    // epilogue: h = relu(acc + b1), s = h . W2 over this thread's 8 cols
    float w2j[8], b1j[8];
    #pragma unroll
    for (int jj = 0; jj < 8; ++jj) {
        int c = (jj < 4) ? (4 * tx + jj) : (60 + 4 * tx + jj);
        w2j[jj] = W2[c];
        b1j[jj] = b1[c];
    }
    float bias2 = b2[0];
    __syncthreads();   // As/Bs -> redv reuse
    #pragma unroll
    for (int i = 0; i < 8; ++i) {
        float s = 0.0f;
        #pragma unroll
        for (int jj = 0; jj < 8; ++jj)
            s += fmaxf(acc[i][jj] + b1j[jj], 0.0f) * w2j[jj];
        redv[ty * 8 + i][tx] = s;
    }
    __syncthreads();
    if (tid < 128) {
        float s = 0.0f;
        #pragma unroll
        for (int t = 0; t < 16; ++t) s += redv[tid][t];
        g[row0 + tid] = s + bias2;
    }
}

// ---------------- Kernel 3: sim = Cn @ En^T, running argmax ----------------
__global__ __launch_bounds__(256, 4) void k_simargmax(
        const float* __restrict__ cn, const float* __restrict__ en,
        float* __restrict__ pmax, int* __restrict__ pidx) {
    __shared__ __align__(16) char smem[2 * 32 * LDSTR * 4];
    float (*As)[LDSTR] = (float(*)[LDSTR])smem;
    float (*Bs)[LDSTR] = (float(*)[LDSTR])(smem + 32 * LDSTR * 4);
    float (*redv)[16]  = (float(*)[16])smem;
    int   (*redi)[16]  = (int(*)[16])(smem + 128 * 16 * 4);

    int b    = blockIdx.y;
    int rb   = blockIdx.x >> 3;    // 0..15
    int ms   = blockIdx.x & 7;     // 0..7
    int row0 = rb * 128;
    int m0   = ms * 256;

    int tid = threadIdx.x;
    int tx = tid & 15, ty = tid >> 4;
    int r  = tid >> 3;
    int kg = tid & 7;

    const float* Abase = cn + ((size_t)b * L_ + row0) * D_;
    const float* Bbase = en + ((size_t)b * L_ + m0) * D_;

    float rmax[8];
    int   ridx[8];
    #pragma unroll
    for (int i = 0; i < 8; ++i) { rmax[i] = -3.0e38f; ridx[i] = 0; }

    for (int nt = 0; nt < 2; ++nt) {
        float acc[8][8];
        #pragma unroll
        for (int i = 0; i < 8; ++i)
            #pragma unroll
            for (int j = 0; j < 8; ++j) acc[i][j] = 0.0f;

        for (int kc = 0; kc < 4; ++kc) {
            __syncthreads();
            #pragma unroll
            for (int p = 0; p < 4; ++p) {
                int rr = r + 32 * p;
                float4 v = *(const float4*)(Abase + (size_t)rr * D_ + kc * 32 + kg * 4);
                As[kg][rr]      = v.x;
                As[8 + kg][rr]  = v.y;
                As[16 + kg][rr] = v.z;
                As[24 + kg][rr] = v.w;
                float4 w = *(const float4*)(Bbase + (size_t)(nt * 128 + rr) * D_ + kc * 32 + kg * 4);
                Bs[kg][rr]      = w.x;
                Bs[8 + kg][rr]  = w.y;
                Bs[16 + kg][rr] = w.z;
                Bs[24 + kg][rr] = w.w;
            }
            __syncthreads();
            #pragma unroll
            for (int k = 0; k < 32; ++k) {
                float a[8], bb[8];
                *(float4*)&a[0]  = *(const float4*)&As[k][ty * 8];
                *(float4*)&a[4]  = *(const float4*)&As[k][ty * 8 + 4];
                *(float4*)&bb[0] = *(const float4*)&Bs[k][tx * 4];
                *(float4*)&bb[4] = *(const float4*)&Bs[k][64 + tx * 4];
                #pragma unroll
                for (int i = 0; i < 8; ++i)
                    #pragma unroll
                    for (int j = 0; j < 8; ++j)
                        acc[i][j] = fmaf(a[i], bb[j], acc[i][j]);
            }
        }
        // running argmax; col(jj) ascends with jj, nt ascends -> strict > keeps lowest m
        #pragma unroll
        for (int i = 0; i < 8; ++i) {
            #pragma unroll
            for (int jj = 0; jj < 8; ++jj) {
                int m = nt * 128 + ((jj < 4) ? (4 * tx + jj) : (60 + 4 * tx + jj));
                if (acc[i][jj] > rmax[i]) { rmax[i] = acc[i][jj]; ridx[i] = m; }
            }
        }
    }

    __syncthreads();   // staging buffers -> reduction buffers reuse
    #pragma unroll
    for (int i = 0; i < 8; ++i) {
        redv[ty * 8 + i][tx] = rmax[i];
        redi[ty * 8 + i][tx] = ridx[i];
    }
    __syncthreads();
    if (tid < 128) {
        float mv = redv[tid][0];
        int   mi = redi[tid][0];
        #pragma unroll
        for (int t = 1; t < 16; ++t) {
            float v = redv[tid][t];
            int  ix = redi[tid][t];
            if (v > mv || (v == mv && ix < mi)) { mv = v; mi = ix; }
        }
        size_t o = ((size_t)b * L_ + row0 + tid) * MSPL + ms;
        pmax[o] = mv;
        pidx[o] = mi + m0;
    }
}

// ---------------- Kernel 4: merge splits + output ----------------
__global__ void k_merge(const float* __restrict__ pmax, const int* __restrict__ pidx,
                        const float* __restrict__ g, float* __restrict__ out) {
    int r = blockIdx.x * 256 + threadIdx.x;
    if (r >= BL_) return;
    float mv = pmax[(size_t)r * MSPL];
    int   mi = pidx[(size_t)r * MSPL];
    #pragma unroll
    for (int s = 1; s < MSPL; ++s) {
        float v = pmax[(size_t)r * MSPL + s];
        int  ix = pidx[(size_t)r * MSPL + s];
        if (v > mv || (v == mv && ix < mi)) { mv = v; mi = ix; }
    }
    int b = r / L_;
    out[r] = g[r] + g[BL_ + (size_t)b * L_ + mi];
}

extern "C" void kernel_launch(void* const* d_in, const int* in_sizes, int n_in,
                              void* d_out, int out_size, void* d_ws, size_t ws_size,
                              hipStream_t stream) {
    const float* context = (const float*)d_in[0];
    const float* W1 = (const float*)d_in[1];
    const float* b1 = (const float*)d_in[2];
    const float* W2 = (const float*)d_in[3];
    const float* b2 = (const float*)d_in[4];
    float* out = (float*)d_out;

    float* ws = (float*)d_ws;
    float* cn   = ws;                               // BL*D
    float* en   = cn + (size_t)BL_ * D_;            // BL*D (contiguous after cn)
    float* g    = en + (size_t)BL_ * D_;            // 2*BL  (g[0..BL)=f(cn), g[BL..2BL)=f(en))
    float* pmax = g + (size_t)2 * BL_;              // BL*MSPL
    int*   pidx = (int*)(pmax + (size_t)BL_ * MSPL);// BL*MSPL

    k_normalize<<<(B_ * 2 * L_) / 4, 256, 0, stream>>>(context, cn, en);
    dim3 g3(16 * MSPL, B_);
    k_simargmax<<<g3, 256, 0, stream>>>(cn, en, pmax, pidx);
    k_feval<<<2 * BL_ / 128, 256, 0, stream>>>(cn, W1, b1, W2, b2, g);
    k_merge<<<BL_ / 256, 256, 0, stream>>>(pmax, pidx, g, out);
}

// Round 3
// 195.941 us; speedup vs baseline: 1.2276x; 1.2276x over previous
//
#include <hip/hip_runtime.h>
#include <hip/hip_bf16.h>

#define B_ 8
#define L_ 2048
#define D_ 128
#define BL_ (B_ * L_)
#define LDSTR 132
#define ASTR 68
#define MSPL 8

// ---------------- Kernel 1: L2 normalize rows ----------------
__global__ void k_normalize(const float* __restrict__ ctx,
                            float* __restrict__ cn, float* __restrict__ en) {
    int wid  = blockIdx.x * 4 + (threadIdx.x >> 6);
    int lane = threadIdx.x & 63;
    int b   = wid / (2 * L_);
    int rem = wid % (2 * L_);
    int c   = rem / L_;
    int l   = rem % L_;

    const float* src = ctx + (size_t)wid * D_;
    float2 v = ((const float2*)src)[lane];
    float ss = v.x * v.x + v.y * v.y;
    #pragma unroll
    for (int off = 32; off; off >>= 1) ss += __shfl_down(ss, off, 64);
    ss = __shfl(ss, 0, 64);
    float inv = 1.0f / fmaxf(sqrtf(ss), 1e-8f);
    float* dst = (c == 0 ? cn : en) + (size_t)(b * L_ + l) * D_;
    ((float2*)dst)[lane] = make_float2(v.x * inv, v.y * inv);
}

// ---------------- Kernel 2: g[r] = relu(X[r]@W1+b1)@W2 + b2 for all 2*BL rows ----------------
// BM=64 tile, micro-tile 4x8, acc[4][8]=32 VGPRs -> no spill, high occupancy.
__global__ void k_feval(
        const float* __restrict__ X,
        const float* __restrict__ W1, const float* __restrict__ b1,
        const float* __restrict__ W2, const float* __restrict__ b2,
        float* __restrict__ g) {
    __shared__ __align__(16) float As[32][ASTR];     // 8.7 KB
    __shared__ __align__(16) float Bs[32][LDSTR];    // 16.9 KB
    __shared__ float redv[64][16];                   // 4 KB

    int tid = threadIdx.x;
    int tx = tid & 15, ty = tid >> 4;   // ty 0..15 -> 4 rows each
    int r  = tid >> 3;                  // 0..31
    int kg = tid & 7;                   // 0..7
    int row0 = blockIdx.x * 64;

    const float* Abase = X + (size_t)row0 * D_;

    float acc[4][8];
    #pragma unroll
    for (int i = 0; i < 4; ++i)
        #pragma unroll
        for (int j = 0; j < 8; ++j) acc[i][j] = 0.0f;

    for (int kc = 0; kc < 4; ++kc) {
        __syncthreads();
        // A tile: 64 rows x 32 k, k-permuted (k=4*kg+i -> phys 8*i+kg)
        #pragma unroll
        for (int p = 0; p < 2; ++p) {
            int rr = r + 32 * p;
            float4 v = *(const float4*)(Abase + (size_t)rr * D_ + kc * 32 + kg * 4);
            As[kg][rr]      = v.x;
            As[8 + kg][rr]  = v.y;
            As[16 + kg][rr] = v.z;
            As[24 + kg][rr] = v.w;
        }
        // B tile: 32 rows of W1, same perm: logical kr -> phys (kr&3)*8 + (kr>>2)
        {
            int kr = r;
            int phys = (kr & 3) * 8 + (kr >> 2);
            const float* src = W1 + (size_t)(kc * 32 + kr) * D_ + kg * 16;
            #pragma unroll
            for (int q = 0; q < 4; ++q)
                *(float4*)&Bs[phys][kg * 16 + q * 4] = *(const float4*)(src + q * 4);
        }
        __syncthreads();
        #pragma unroll
        for (int k = 0; k < 32; ++k) {
            float a[4], bb[8];
            *(float4*)&a[0]  = *(const float4*)&As[k][ty * 4];
            *(float4*)&bb[0] = *(const float4*)&Bs[k][tx * 4];
            *(float4*)&bb[4] = *(const float4*)&Bs[k][64 + tx * 4];
            #pragma unroll
            for (int i = 0; i < 4; ++i)
                #pragma unroll
                for (int j = 0; j < 8; ++j)
                    acc[i][j] = fmaf(a[i], bb[j], acc[i][j]);
        }
    }

    // epilogue: s = relu(acc + b1) . W2 over this thread's 8 cols
    float w2j[8], b1j[8];
    #pragma unroll
    for (int jj = 0; jj < 8; ++jj) {
        int c = (jj < 4) ? (4 * tx + jj) : (60 + 4 * tx + jj);
        w2j[jj] = W2[c];
        b1j[jj] = b1[c];
    }
    float bias2 = b2[0];
    __syncthreads();
    #pragma unroll
    for (int i = 0; i < 4; ++i) {
        float s = 0.0f;
        #pragma unroll
        for (int jj = 0; jj < 8; ++jj)
            s += fmaxf(acc[i][jj] + b1j[jj], 0.0f) * w2j[jj];
        redv[ty * 4 + i][tx] = s;
    }
    __syncthreads();
    if (tid < 64) {
        float s = 0.0f;
        #pragma unroll
        for (int t = 0; t < 16; ++t) s += redv[tid][t];
        g[row0 + tid] = s + bias2;
    }
}

// ---------------- Kernel 3: sim = Cn @ En^T, running argmax ----------------
// XCD swizzle: batch = blockIdx.x & 7 -> all blocks of batch b on XCD b
// (per-batch working set cn_b+en_b = 2 MB fits the 4 MB XCD L2).
__global__ __launch_bounds__(256, 2) void k_simargmax(
        const float* __restrict__ cn, const float* __restrict__ en,
        float* __restrict__ pmax, int* __restrict__ pidx) {
    __shared__ __align__(16) char smem[2 * 32 * LDSTR * 4];
    float (*As)[LDSTR] = (float(*)[LDSTR])smem;
    float (*Bs)[LDSTR] = (float(*)[LDSTR])(smem + 32 * LDSTR * 4);
    float (*redv)[16]  = (float(*)[16])smem;
    int   (*redi)[16]  = (int(*)[16])(smem + 128 * 16 * 4);

    int bid  = blockIdx.x;
    int b    = bid & 7;            // XCD id
    int t2   = bid >> 3;           // 0..127
    int rb   = t2 & 15;            // 0..15
    int ms   = t2 >> 4;            // 0..7
    int row0 = rb * 128;
    int m0   = ms * 256;

    int tid = threadIdx.x;
    int tx = tid & 15, ty = tid >> 4;
    int r  = tid >> 3;
    int kg = tid & 7;

    const float* Abase = cn + ((size_t)b * L_ + row0) * D_;
    const float* Bbase = en + ((size_t)b * L_ + m0) * D_;

    float rmax[8];
    int   ridx[8];
    #pragma unroll
    for (int i = 0; i < 8; ++i) { rmax[i] = -3.0e38f; ridx[i] = 0; }

    for (int nt = 0; nt < 2; ++nt) {
        float acc[8][8];
        #pragma unroll
        for (int i = 0; i < 8; ++i)
            #pragma unroll
            for (int j = 0; j < 8; ++j) acc[i][j] = 0.0f;

        for (int kc = 0; kc < 4; ++kc) {
            __syncthreads();
            #pragma unroll
            for (int p = 0; p < 4; ++p) {
                int rr = r + 32 * p;
                float4 v = *(const float4*)(Abase + (size_t)rr * D_ + kc * 32 + kg * 4);
                As[kg][rr]      = v.x;
                As[8 + kg][rr]  = v.y;
                As[16 + kg][rr] = v.z;
                As[24 + kg][rr] = v.w;
                float4 w = *(const float4*)(Bbase + (size_t)(nt * 128 + rr) * D_ + kc * 32 + kg * 4);
                Bs[kg][rr]      = w.x;
                Bs[8 + kg][rr]  = w.y;
                Bs[16 + kg][rr] = w.z;
                Bs[24 + kg][rr] = w.w;
            }
            __syncthreads();
            #pragma unroll
            for (int k = 0; k < 32; ++k) {
                float a[8], bb[8];
                *(float4*)&a[0]  = *(const float4*)&As[k][ty * 8];
                *(float4*)&a[4]  = *(const float4*)&As[k][ty * 8 + 4];
                *(float4*)&bb[0] = *(const float4*)&Bs[k][tx * 4];
                *(float4*)&bb[4] = *(const float4*)&Bs[k][64 + tx * 4];
                #pragma unroll
                for (int i = 0; i < 8; ++i)
                    #pragma unroll
                    for (int j = 0; j < 8; ++j)
                        acc[i][j] = fmaf(a[i], bb[j], acc[i][j]);
            }
        }
        // running argmax; col(jj) ascends with jj, nt ascends -> strict > keeps lowest m
        #pragma unroll
        for (int i = 0; i < 8; ++i) {
            #pragma unroll
            for (int jj = 0; jj < 8; ++jj) {
                int m = nt * 128 + ((jj < 4) ? (4 * tx + jj) : (60 + 4 * tx + jj));
                if (acc[i][jj] > rmax[i]) { rmax[i] = acc[i][jj]; ridx[i] = m; }
            }
        }
    }

    __syncthreads();
    #pragma unroll
    for (int i = 0; i < 8; ++i) {
        redv[ty * 8 + i][tx] = rmax[i];
        redi[ty * 8 + i][tx] = ridx[i];
    }
    __syncthreads();
    if (tid < 128) {
        float mv = redv[tid][0];
        int   mi = redi[tid][0];
        #pragma unroll
        for (int t = 1; t < 16; ++t) {
            float v = redv[tid][t];
            int  ix = redi[tid][t];
            if (v > mv || (v == mv && ix < mi)) { mv = v; mi = ix; }
        }
        size_t o = ((size_t)b * L_ + row0 + tid) * MSPL + ms;
        pmax[o] = mv;
        pidx[o] = mi + m0;
    }
}

// ---------------- Kernel 4: merge splits + output ----------------
__global__ void k_merge(const float* __restrict__ pmax, const int* __restrict__ pidx,
                        const float* __restrict__ g, float* __restrict__ out) {
    int r = blockIdx.x * 256 + threadIdx.x;
    if (r >= BL_) return;
    float mv = pmax[(size_t)r * MSPL];
    int   mi = pidx[(size_t)r * MSPL];
    #pragma unroll
    for (int s = 1; s < MSPL; ++s) {
        float v = pmax[(size_t)r * MSPL + s];
        int  ix = pidx[(size_t)r * MSPL + s];
        if (v > mv || (v == mv && ix < mi)) { mv = v; mi = ix; }
    }
    int b = r / L_;
    out[r] = g[r] + g[BL_ + (size_t)b * L_ + mi];
}

extern "C" void kernel_launch(void* const* d_in, const int* in_sizes, int n_in,
                              void* d_out, int out_size, void* d_ws, size_t ws_size,
                              hipStream_t stream) {
    const float* context = (const float*)d_in[0];
    const float* W1 = (const float*)d_in[1];
    const float* b1 = (const float*)d_in[2];
    const float* W2 = (const float*)d_in[3];
    const float* b2 = (const float*)d_in[4];
    float* out = (float*)d_out;

    float* ws = (float*)d_ws;
    float* cn   = ws;                               // BL*D
    float* en   = cn + (size_t)BL_ * D_;            // BL*D (contiguous after cn)
    float* g    = en + (size_t)BL_ * D_;            // 2*BL
    float* pmax = g + (size_t)2 * BL_;              // BL*MSPL
    int*   pidx = (int*)(pmax + (size_t)BL_ * MSPL);// BL*MSPL

    k_normalize<<<(B_ * 2 * L_) / 4, 256, 0, stream>>>(context, cn, en);
    k_simargmax<<<16 * MSPL * B_, 256, 0, stream>>>(cn, en, pmax, pidx);
    k_feval<<<2 * BL_ / 64, 256, 0, stream>>>(cn, W1, b1, W2, b2, g);
    k_merge<<<BL_ / 256, 256, 0, stream>>>(pmax, pidx, g, out);
}